// Round 1
// baseline (244.172 us; speedup 1.0000x reference)
//
#include <hip/hip_runtime.h>
#include <hip/hip_bf16.h>
#include <stdint.h>

// ---- types ----
typedef __attribute__((ext_vector_type(8))) short s16x8;   // 8 bf16 (4 VGPR) MFMA frag
typedef __attribute__((ext_vector_type(4))) float f32x4v;  // MFMA accum

typedef const void __attribute__((address_space(1)))* gas_ptr;
typedef void __attribute__((address_space(3)))* las_ptr;
#define GLD16(g, l) __builtin_amdgcn_global_load_lds((gas_ptr)(g), (las_ptr)(l), 16, 0, 0)

// ---- problem sizes ----
#define NIMG 32
#define CIN  256
#define HWDIM 56
#define HPAD 58
#define OCH  256
#define SPATIAL (HWDIM*HWDIM)        // 3136
#define M_TOT (NIMG*SPATIAL)         // 100352
#define KTOT  2304                    // 9*256

// workspace layout (bytes)
#define XB_BYTES   55115776ull        // 32*58*58*256*2
#define WT_OFF     55115776ull
#define WT_BYTES   1179648ull         // 256*2304*2
#define ALPHA_OFF  56295424ull

// =====================================================================
// Kernel 1: per-o alpha + ternary weights, transposed to WT[o][k], k = tap*256 + c
// =====================================================================
__global__ __launch_bounds__(256)
void prep_weights(const float* __restrict__ w1, const float* __restrict__ w2,
                  __hip_bfloat16* __restrict__ WT, float* __restrict__ alpha) {
    const int o = blockIdx.x;
    const int t = threadIdx.x;
    const float* p1 = w1 + o * KTOT;
    const float* p2 = w2 + o * KTOT;
    __hip_bfloat16* wo = WT + o * KTOT;

    float s1 = 0.f, s2 = 0.f;
    for (int i = t; i < KTOT; i += 256) {
        float a = p1[i], b = p2[i];
        s1 += fabsf(a);
        s2 += fabsf(b);
        float sg = ((a > 0.f) ? 1.f : ((a < 0.f) ? -1.f : 0.f))
                 + ((b > 0.f) ? 1.f : ((b < 0.f) ? -1.f : 0.f));
        int c = i / 9;
        int tap = i - c * 9;            // w layout [o][c][3][3] -> inner = c*9 + tap
        wo[tap * 256 + c] = __float2bfloat16(sg);
    }
    // block reduction
    __shared__ float red[8];
    #pragma unroll
    for (int off = 32; off > 0; off >>= 1) {
        s1 += __shfl_down(s1, off, 64);
        s2 += __shfl_down(s2, off, 64);
    }
    const int lane = t & 63, wv = t >> 6;
    if (lane == 0) { red[wv] = s1; red[4 + wv] = s2; }
    __syncthreads();
    if (t == 0) {
        float t1 = red[0] + red[1] + red[2] + red[3];
        float t2 = red[4] + red[5] + red[6] + red[7];
        alpha[o] = (t1 * (1.f / 2304.f) + t2 * (1.f / 2304.f)) * 0.5f;
    }
}

// =====================================================================
// Kernel 2: binarize + NCHW->padded NHWC transpose.
// xb[n][hp][wp][c], hp/wp in [0,58); border stays 0 (memset).
// One block per (n, h): reads 256 rows of 56 floats, writes 56*256 bf16.
// =====================================================================
__global__ __launch_bounds__(256)
void binarize_kernel(const float* __restrict__ x, __hip_bfloat16* __restrict__ xb) {
    __shared__ __hip_bfloat16 tile[HWDIM * 258];   // [w][c], stride 258 breaks bank conflicts
    const int b = blockIdx.x;
    const int n = b / HWDIM;
    const int h = b % HWDIM;
    const int t = threadIdx.x;

    const float* xp = x + (size_t)n * (CIN * SPATIAL) + (size_t)h * HWDIM;
    if (t < 224) {
        const int w  = t % HWDIM;
        const int cl = t / HWDIM;     // 0..3
        for (int c0 = 0; c0 < CIN; c0 += 4) {
            int c = c0 + cl;
            float v = xp[(size_t)c * SPATIAL + w];
            float s = (v > 0.f) ? 1.f : ((v < 0.f) ? -1.f : 0.f);
            tile[w * 258 + c] = __float2bfloat16(s);
        }
    }
    __syncthreads();
    // drain: thread t owns channel c=t, loop w; writes are 512B contiguous per w
    __hip_bfloat16* op = xb + (((size_t)n * HPAD + (h + 1)) * HPAD + 1) * CIN + t;
    for (int w = 0; w < HWDIM; ++w) {
        op[(size_t)w * CIN] = tile[w * 258 + t];
    }
}

// =====================================================================
// Kernel 3: implicit-GEMM ternary conv.
// D[o][sp] = sum_k WT[o][k] * patch[sp][k];  out = D * alpha[o]
// Tile 128(o) x 128(sp), BK=64, 4 waves, each wave 64x64 (acc[4][4] of 16x16).
// A-operand (M=o) from Ws[o][k]; B-operand (N=sp) from As[sp][k].
// =====================================================================
__global__ __launch_bounds__(256)
void conv_kernel(const __hip_bfloat16* __restrict__ xb,
                 const __hip_bfloat16* __restrict__ WT,
                 const float* __restrict__ alpha,
                 float* __restrict__ out) {
    __shared__ __align__(16) __hip_bfloat16 As[128 * 64];  // patches [sp][k]
    __shared__ __align__(16) __hip_bfloat16 Ws[128 * 64];  // weights [o][k]

    const int t    = threadIdx.x;
    const int lane = t & 63;
    const int wv   = t >> 6;
    const int bid  = blockIdx.x;
    const int nt   = bid & 1;         // o-tile
    const int mt   = bid >> 1;        // spatial tile
    const int m0   = mt * 128;
    const int o0   = nt * 128;

    // ---- per-thread staging bases ----
    // A: thread t, round ro -> tile row r = (t>>3)+ro*32 (spatial), c0=(t&7)*8
    const __hip_bfloat16* a_g[4];
    #pragma unroll
    for (int ro = 0; ro < 4; ++ro) {
        int r  = (t >> 3) + ro * 32;
        int m  = m0 + r;
        int ni = m / SPATIAL;
        int sp = m - ni * SPATIAL;
        int h  = sp / HWDIM;
        int w  = sp - h * HWDIM;
        a_g[ro] = xb + ((size_t)(ni * HPAD + h) * HPAD + w) * CIN + (t & 7) * 8;
    }
    // W: row r = (t>>3)+ro*32 (o), c0=(t&7)*8
    const __hip_bfloat16* w_g = WT + (size_t)(o0 + (t >> 3)) * KTOT + (t & 7) * 8;

    char* As_b = (char*)As;
    char* Ws_b = (char*)Ws;
    const int lds_wave = wv * 1024;   // byte offset of this wave's 64 lanes*16B slot

    f32x4v acc[4][4];
    #pragma unroll
    for (int i = 0; i < 4; ++i)
        #pragma unroll
        for (int j = 0; j < 4; ++j)
            acc[i][j] = (f32x4v){0.f, 0.f, 0.f, 0.f};

    const int row = lane & 15;
    const int kq  = (lane >> 4) * 8;
    const int wo  = (wv >> 1) * 64;   // wave's o offset in tile
    const int wm  = (wv & 1) * 64;    // wave's spatial offset in tile

    for (int tap = 0; tap < 9; ++tap) {
        const int kh = tap / 3, kw = tap - kh * 3;
        const int aoff_tap = (kh * HPAD + kw) * CIN;   // padded-coord shift
        for (int cb = 0; cb < 4; ++cb) {
            const int ks   = tap * 256 + cb * 64;      // global k start
            const int aoff = aoff_tap + cb * 64;
            #pragma unroll
            for (int ro = 0; ro < 4; ++ro)
                GLD16(a_g[ro] + aoff, As_b + lds_wave + ro * 4096);
            #pragma unroll
            for (int ro = 0; ro < 4; ++ro)
                GLD16(w_g + (size_t)ro * 32 * KTOT + ks, Ws_b + lds_wave + ro * 4096);
            asm volatile("s_waitcnt vmcnt(0)" ::: "memory");
            __syncthreads();

            #pragma unroll
            for (int kk = 0; kk < 2; ++kk) {
                s16x8 af[4], bf[4];
                #pragma unroll
                for (int i = 0; i < 4; ++i)
                    af[i] = *(const s16x8*)&Ws[(wo + i * 16 + row) * 64 + kk * 32 + kq];
                #pragma unroll
                for (int j = 0; j < 4; ++j)
                    bf[j] = *(const s16x8*)&As[(wm + j * 16 + row) * 64 + kk * 32 + kq];
                #pragma unroll
                for (int i = 0; i < 4; ++i)
                    #pragma unroll
                    for (int j = 0; j < 4; ++j)
                        acc[i][j] = __builtin_amdgcn_mfma_f32_16x16x32_bf16(
                            af[i], bf[j], acc[i][j], 0, 0, 0);
            }
            __syncthreads();
        }
    }

    // ---- epilogue: out[n][o][h][w] = acc * alpha[o] ----
    // D frag: col(sp) = lane&15, row(o) = (lane>>4)*4 + reg
    float al[4][4];
    #pragma unroll
    for (int i = 0; i < 4; ++i) {
        int ob = o0 + wo + i * 16 + (lane >> 4) * 4;
        #pragma unroll
        for (int r = 0; r < 4; ++r) al[i][r] = alpha[ob + r];
    }
    #pragma unroll
    for (int j = 0; j < 4; ++j) {
        int m  = m0 + wm + j * 16 + (lane & 15);
        int ni = m / SPATIAL;
        int sp = m - ni * SPATIAL;
        long base = (long)ni * (OCH * SPATIAL) + sp;
        #pragma unroll
        for (int i = 0; i < 4; ++i) {
            int ob = o0 + wo + i * 16 + (lane >> 4) * 4;
            #pragma unroll
            for (int r = 0; r < 4; ++r) {
                out[base + (long)(ob + r) * SPATIAL] = acc[i][j][r] * al[i][r];
            }
        }
    }
}

// =====================================================================
extern "C" void kernel_launch(void* const* d_in, const int* in_sizes, int n_in,
                              void* d_out, int out_size, void* d_ws, size_t ws_size,
                              hipStream_t stream) {
    const float* x  = (const float*)d_in[0];
    const float* w1 = (const float*)d_in[1];
    const float* w2 = (const float*)d_in[2];
    float* out = (float*)d_out;

    char* ws = (char*)d_ws;
    __hip_bfloat16* xb    = (__hip_bfloat16*)ws;
    __hip_bfloat16* WT    = (__hip_bfloat16*)(ws + WT_OFF);
    float*          alpha = (float*)(ws + ALPHA_OFF);

    // zero padded binarized buffer (borders must be 0)
    hipMemsetAsync(xb, 0, XB_BYTES, stream);

    hipLaunchKernelGGL(prep_weights, dim3(OCH), dim3(256), 0, stream, w1, w2, WT, alpha);
    hipLaunchKernelGGL(binarize_kernel, dim3(NIMG * HWDIM), dim3(256), 0, stream, x, xb);
    hipLaunchKernelGGL(conv_kernel, dim3((M_TOT / 128) * 2), dim3(256), 0, stream,
                       xb, WT, alpha, out);
}

// Round 2
// 139.166 us; speedup vs baseline: 1.7545x; 1.7545x over previous
//
#include <hip/hip_runtime.h>
#include <hip/hip_bf16.h>
#include <stdint.h>

// ---- types ----
typedef __attribute__((ext_vector_type(4))) int i32x4;   // 16 i8 (4 VGPR) MFMA frag / i32 accum

typedef const void __attribute__((address_space(1)))* gas_ptr;
typedef void __attribute__((address_space(3)))* las_ptr;
#define GLD16(g, l) __builtin_amdgcn_global_load_lds((gas_ptr)(g), (las_ptr)(l), 16, 0, 0)

// ---- problem sizes ----
#define NIMG 32
#define CIN  256
#define HWDIM 56
#define HPAD 58
#define OCH  256
#define SPATIAL (HWDIM*HWDIM)        // 3136
#define M_TOT (NIMG*SPATIAL)         // 100352
#define KTOT  2304                    // 9*256
#define NSTEP 36                      // K-steps of 64

// workspace layout (bytes)
#define XB_BYTES   27557888ull        // 32*58*58*256 i8
#define WT_OFF     27557888ull
#define ALPHA_OFF  28147712ull        // + 256*2304 i8

// =====================================================================
// Kernel 1: per-o alpha + ternary i8 weights transposed to WT[o][k], k = tap*256 + c
// =====================================================================
__global__ __launch_bounds__(256)
void prep_weights(const float* __restrict__ w1, const float* __restrict__ w2,
                  char* __restrict__ WT, float* __restrict__ alpha) {
    const int o = blockIdx.x;
    const int t = threadIdx.x;
    const float* p1 = w1 + o * KTOT;
    const float* p2 = w2 + o * KTOT;
    char* wo = WT + o * KTOT;

    float s1 = 0.f, s2 = 0.f;
    for (int i = t; i < KTOT; i += 256) {
        float a = p1[i], b = p2[i];
        s1 += fabsf(a);
        s2 += fabsf(b);
        int sg = ((a > 0.f) ? 1 : ((a < 0.f) ? -1 : 0))
               + ((b > 0.f) ? 1 : ((b < 0.f) ? -1 : 0));
        int c = i / 9;
        int tap = i - c * 9;            // w layout [o][c][3][3] -> inner = c*9 + tap
        wo[tap * 256 + c] = (char)sg;
    }
    __shared__ float red[8];
    #pragma unroll
    for (int off = 32; off > 0; off >>= 1) {
        s1 += __shfl_down(s1, off, 64);
        s2 += __shfl_down(s2, off, 64);
    }
    const int lane = t & 63, wv = t >> 6;
    if (lane == 0) { red[wv] = s1; red[4 + wv] = s2; }
    __syncthreads();
    if (t == 0) {
        float t1 = red[0] + red[1] + red[2] + red[3];
        float t2 = red[4] + red[5] + red[6] + red[7];
        alpha[o] = (t1 * (1.f / 2304.f) + t2 * (1.f / 2304.f)) * 0.5f;
    }
}

// =====================================================================
// Kernel 2: binarize + NCHW -> padded NHWC i8 transpose.
// xb[n][hp][wp][c], border stays 0 (memset). One block per (n,h).
// =====================================================================
__global__ __launch_bounds__(256)
void binarize_kernel(const float* __restrict__ x, char* __restrict__ xb) {
    __shared__ __align__(4) char tile[HWDIM * 260];  // [w][c], stride 260 (4-aligned, odd dwords)
    const int b = blockIdx.x;
    const int n = b / HWDIM;
    const int h = b % HWDIM;
    const int t = threadIdx.x;

    if (t < 224) {
        const int w  = t % HWDIM;
        const int cl = t / HWDIM;     // 0..3
        const float* xp = x + (size_t)n * (CIN * SPATIAL) + (size_t)h * HWDIM + w;
        for (int c0 = 0; c0 < CIN; c0 += 4) {
            int c = c0 + cl;
            float v = xp[(size_t)c * SPATIAL];
            tile[w * 260 + c] = (v > 0.f) ? 1 : ((v < 0.f) ? -1 : 0);
        }
    }
    __syncthreads();
    // drain: wave wv handles row w = w0+wv; lane writes 4 channels (4B) -> 256B/wave coalesced
    const int wv = t >> 6, lane = t & 63;
    char* op = xb + (((size_t)n * HPAD + (h + 1)) * HPAD + 1) * CIN;
    for (int w0 = 0; w0 < HWDIM; w0 += 4) {
        int w = w0 + wv;
        int val = *(const int*)&tile[w * 260 + lane * 4];
        *(int*)(op + (size_t)w * CIN + lane * 4) = val;
    }
}

// =====================================================================
// Kernel 3: i8 implicit-GEMM ternary conv, double-buffered 2-phase pipeline.
// D[o][sp] = sum_k WT[o][k] * patch[sp][k];  out = (float)D * alpha[o]
// Tile 128(o) x 128(sp), BK=64 i8, 4 waves, each wave 64x64 (acc[4][4] of 16x16).
// LDS per buffer: Ws 128x64 i8 (8KB) + As 128x64 i8 (8KB); dbuf = 32KB.
// =====================================================================
__global__ __launch_bounds__(256)
void conv_kernel(const char* __restrict__ xb,
                 const char* __restrict__ WT,
                 const float* __restrict__ alpha,
                 float* __restrict__ out) {
    __shared__ __align__(16) char lds[2][16384];   // [buf][ Ws(8KB) | As(8KB) ]

    const int t    = threadIdx.x;
    const int lane = t & 63;
    const int wv   = t >> 6;
    const int bid  = blockIdx.x;
    const int nt   = bid & 1;         // o-tile
    const int mt   = bid >> 1;        // spatial tile
    const int m0   = mt * 128;
    const int o0   = nt * 128;

    // ---- per-thread staging bases ----
    // rows r = (t>>2) + ro*64, col bytes (t&3)*16  (64 i8 per row)
    const char* a_base0;
    const char* a_base1;
    {
        #pragma unroll
        for (int ro = 0; ro < 2; ++ro) {
            int r  = (t >> 2) + ro * 64;
            int m  = m0 + r;
            int ni = m / SPATIAL;
            int sp = m - ni * SPATIAL;
            int h  = sp / HWDIM;
            int w  = sp - h * HWDIM;
            const char* p = xb + ((size_t)(ni * HPAD + h) * HPAD + w) * CIN + (t & 3) * 16;
            if (ro == 0) a_base0 = p; else a_base1 = p;
        }
    }
    const char* w_base0 = WT + (size_t)(o0 + (t >> 2)) * KTOT + (t & 3) * 16;
    const char* w_base1 = w_base0 + (size_t)64 * KTOT;

    i32x4 acc[4][4];
    #pragma unroll
    for (int i = 0; i < 4; ++i)
        #pragma unroll
        for (int j = 0; j < 4; ++j)
            acc[i][j] = (i32x4){0, 0, 0, 0};

    const int rl = lane & 15;
    const int kq = (lane >> 4) * 16;  // 16 contiguous k-bytes per lane group
    const int wo = (wv >> 1) * 64;    // wave's o offset in tile
    const int wm = (wv & 1) * 64;     // wave's spatial offset in tile

    // stage K-step s into buffer `base`
    auto STAGE = [&](int s, char* base) {
        int tap  = s >> 2;                                  // 0..8
        int kh   = tap / 3, kw = tap - kh * 3;
        int aoff = (kh * HPAD + kw) * CIN + (s & 3) * 64;   // padded-coord shift + c-block
        int woff = s * 64;                                  // k = s*64 in WT
        GLD16(w_base0 + woff, base + t * 16);
        GLD16(w_base1 + woff, base + 4096 + t * 16);
        GLD16(a_base0 + aoff, base + 8192 + t * 16);
        GLD16(a_base1 + aoff, base + 8192 + 4096 + t * 16);
    };

    // prologue
    STAGE(0, &lds[0][0]);
    asm volatile("s_waitcnt vmcnt(0)" ::: "memory");
    __syncthreads();

    int cur = 0;
    for (int s = 0; s < NSTEP; ++s) {
        if (s + 1 < NSTEP) STAGE(s + 1, &lds[cur ^ 1][0]);

        const char* Wb = &lds[cur][0];
        const char* Ab = &lds[cur][8192];
        i32x4 af[4], bf[4];
        #pragma unroll
        for (int i = 0; i < 4; ++i)
            af[i] = *(const i32x4*)(Wb + (wo + i * 16 + rl) * 64 + kq);
        #pragma unroll
        for (int j = 0; j < 4; ++j)
            bf[j] = *(const i32x4*)(Ab + (wm + j * 16 + rl) * 64 + kq);
        #pragma unroll
        for (int i = 0; i < 4; ++i)
            #pragma unroll
            for (int j = 0; j < 4; ++j)
                acc[i][j] = __builtin_amdgcn_mfma_i32_16x16x64_i8(
                    af[i], bf[j], acc[i][j], 0, 0, 0);

        asm volatile("s_waitcnt vmcnt(0)" ::: "memory");
        __syncthreads();
        cur ^= 1;
    }

    // ---- epilogue: out[n][o][h][w] = acc * alpha[o] ----
    // D frag: col(sp) = lane&15, row(o) = (lane>>4)*4 + reg
    float al[4][4];
    #pragma unroll
    for (int i = 0; i < 4; ++i) {
        int ob = o0 + wo + i * 16 + (lane >> 4) * 4;
        #pragma unroll
        for (int r = 0; r < 4; ++r) al[i][r] = alpha[ob + r];
    }
    #pragma unroll
    for (int j = 0; j < 4; ++j) {
        int m  = m0 + wm + j * 16 + (lane & 15);
        int ni = m / SPATIAL;
        int sp = m - ni * SPATIAL;
        long base = (long)ni * (OCH * SPATIAL) + sp;
        #pragma unroll
        for (int i = 0; i < 4; ++i) {
            int ob = o0 + wo + i * 16 + (lane >> 4) * 4;
            #pragma unroll
            for (int r = 0; r < 4; ++r) {
                out[base + (long)(ob + r) * SPATIAL] = (float)acc[i][j][r] * al[i][r];
            }
        }
    }
}

// =====================================================================
extern "C" void kernel_launch(void* const* d_in, const int* in_sizes, int n_in,
                              void* d_out, int out_size, void* d_ws, size_t ws_size,
                              hipStream_t stream) {
    const float* x  = (const float*)d_in[0];
    const float* w1 = (const float*)d_in[1];
    const float* w2 = (const float*)d_in[2];
    float* out = (float*)d_out;

    char* ws = (char*)d_ws;
    char*  xb    = ws;
    char*  WT    = ws + WT_OFF;
    float* alpha = (float*)(ws + ALPHA_OFF);

    // zero padded binarized buffer (borders must be 0)
    hipMemsetAsync(xb, 0, XB_BYTES, stream);

    hipLaunchKernelGGL(prep_weights, dim3(OCH), dim3(256), 0, stream, w1, w2, WT, alpha);
    hipLaunchKernelGGL(binarize_kernel, dim3(NIMG * HWDIM), dim3(256), 0, stream, x, xb);
    hipLaunchKernelGGL(conv_kernel, dim3((M_TOT / 128) * 2), dim3(256), 0, stream,
                       xb, WT, alpha, out);
}

// Round 3
// 107.552 us; speedup vs baseline: 2.2703x; 1.2939x over previous
//
#include <hip/hip_runtime.h>
#include <hip/hip_bf16.h>
#include <stdint.h>

// ---- types ----
typedef __attribute__((ext_vector_type(4))) int i32x4;   // 16 i8 MFMA frag / i32x4 accum

typedef const void __attribute__((address_space(1)))* gas_ptr;
typedef void __attribute__((address_space(3)))* las_ptr;
#define GLD16(g, l) __builtin_amdgcn_global_load_lds((gas_ptr)(g), (las_ptr)(l), 16, 0, 0)

// ---- problem sizes ----
#define NIMG 32
#define CIN  256
#define HWDIM 56
#define HPAD 58
#define OCH  256
#define SPATIAL (HWDIM*HWDIM)        // 3136
#define M_TOT (NIMG*SPATIAL)         // 100352
#define KTOT  2304                    // 9*256
#define NSTEP 36                      // K-steps of 64 i8

// workspace layout (bytes)
#define WT_OFF     27557888ull        // after xb: 32*58*58*256 i8
#define ALPHA_OFF  28147712ull        // after WT: 256*2304 i8

// =====================================================================
// Kernel 1: per-o alpha + ternary i8 weights transposed to WT[o][k], k = tap*256 + c
// =====================================================================
__global__ __launch_bounds__(256)
void prep_weights(const float* __restrict__ w1, const float* __restrict__ w2,
                  char* __restrict__ WT, float* __restrict__ alpha) {
    const int o = blockIdx.x;
    const int t = threadIdx.x;
    const float* p1 = w1 + o * KTOT;
    const float* p2 = w2 + o * KTOT;
    char* wo = WT + o * KTOT;

    float s1 = 0.f, s2 = 0.f;
    for (int i = t; i < KTOT; i += 256) {
        float a = p1[i], b = p2[i];
        s1 += fabsf(a);
        s2 += fabsf(b);
        int sg = ((a > 0.f) ? 1 : ((a < 0.f) ? -1 : 0))
               + ((b > 0.f) ? 1 : ((b < 0.f) ? -1 : 0));
        int c = i / 9;
        int tap = i - c * 9;
        wo[tap * 256 + c] = (char)sg;
    }
    __shared__ float red[8];
    #pragma unroll
    for (int off = 32; off > 0; off >>= 1) {
        s1 += __shfl_down(s1, off, 64);
        s2 += __shfl_down(s2, off, 64);
    }
    const int lane = t & 63, wv = t >> 6;
    if (lane == 0) { red[wv] = s1; red[4 + wv] = s2; }
    __syncthreads();
    if (t == 0) {
        float t1 = red[0] + red[1] + red[2] + red[3];
        float t2 = red[4] + red[5] + red[6] + red[7];
        alpha[o] = (t1 * (1.f / 2304.f) + t2 * (1.f / 2304.f)) * 0.5f;
    }
}

// =====================================================================
// Kernel 2: binarize + NCHW -> padded NHWC i8, including border zeroing
// (replaces the 27.5MB memset). Grid = 32 * 58 blocks: one per (n, hp).
// =====================================================================
__global__ __launch_bounds__(256)
void binarize_kernel(const float* __restrict__ x, char* __restrict__ xb) {
    const int b  = blockIdx.x;
    const int n  = b / HPAD;
    const int hp = b % HPAD;
    const int t  = threadIdx.x;
    char* rowp = xb + ((size_t)n * HPAD + hp) * (HPAD * CIN);

    if (hp == 0 || hp == HPAD - 1) {
        int* ip = (int*)rowp;                 // 58*256 B = 3712 ints
        for (int i = t; i < 3712; i += 256) ip[i] = 0;
        return;
    }
    const int h = hp - 1;
    __shared__ __align__(4) char tile[HWDIM * 260];
    if (t < 224) {
        const int w  = t % HWDIM;
        const int cl = t / HWDIM;
        const float* xp = x + (size_t)n * (CIN * SPATIAL) + (size_t)h * HWDIM + w;
        for (int c0 = 0; c0 < CIN; c0 += 4) {
            int c = c0 + cl;
            float v = xp[(size_t)c * SPATIAL];
            tile[w * 260 + c] = (v > 0.f) ? 1 : ((v < 0.f) ? -1 : 0);
        }
    }
    // zero left/right pad columns of this row
    int* ip = (int*)rowp;
    if (t < 64) ip[t] = 0;                    // w = 0
    else if (t < 128) ip[3648 + (t - 64)] = 0;// w = 57
    __syncthreads();
    const int wv = t >> 6, lane = t & 63;
    char* op = rowp + CIN;                    // w starts at 1
    for (int w0 = 0; w0 < HWDIM; w0 += 4) {
        int w = w0 + wv;
        int val = *(const int*)&tile[w * 260 + lane * 4];
        *(int*)(op + (size_t)w * CIN + lane * 4) = val;
    }
}

// =====================================================================
// Kernel 3: i8 implicit-GEMM, ring-4 LDS + counted vmcnt + raw barrier (T4),
// 16B XOR swizzle (T2, both-sides), XCD-bijective tile remap (T1).
// Tile 128(o) x 128(sp), BK=64 i8, 4 waves, wave = 64x64 (acc[4][4] of 16x16x64).
// =====================================================================
__global__ __launch_bounds__(256)
void conv_kernel(const char* __restrict__ xb,
                 const char* __restrict__ WT,
                 const float* __restrict__ alpha,
                 float* __restrict__ out) {
    __shared__ __align__(16) char lds[4][16384];   // ring: [buf][ W(8KB) | A(8KB) ]
    char* lds_flat = &lds[0][0];

    const int t    = threadIdx.x;
    const int lane = t & 63;
    const int wv   = t >> 6;

    // XCD-aware bijective remap: 1568 blocks = 8 XCDs * 196 tiles
    const int bid  = blockIdx.x;
    const int tid_ = (bid & 7) * 196 + (bid >> 3);
    const int nt   = tid_ & 1;
    const int mt   = tid_ >> 1;
    const int m0   = mt * 128;
    const int o0   = nt * 128;

    // ---- staging sources: thread t covers rows srow & srow+64, swizzled 16B col ----
    const int srow = t >> 2;
    const int scol = ((t & 3) ^ (srow & 3)) * 16;   // pre-swizzled global column
    const char* a_g0; const char* a_g1;
    {
        int m, ni, sp, h, w;
        m = m0 + srow;      ni = m / SPATIAL; sp = m - ni * SPATIAL; h = sp / HWDIM; w = sp - h * HWDIM;
        a_g0 = xb + ((size_t)(ni * HPAD + h) * HPAD + w) * CIN + scol;
        m = m0 + srow + 64; ni = m / SPATIAL; sp = m - ni * SPATIAL; h = sp / HWDIM; w = sp - h * HWDIM;
        a_g1 = xb + ((size_t)(ni * HPAD + h) * HPAD + w) * CIN + scol;
    }
    const char* w_g0 = WT + (size_t)(o0 + srow) * KTOT + scol;
    const char* w_g1 = w_g0 + (size_t)64 * KTOT;

    char* lds_dst = lds_flat + t * 16;   // linear dest (HW: firstlane base + lane*16)

    i32x4 acc[4][4];
    #pragma unroll
    for (int i = 0; i < 4; ++i)
        #pragma unroll
        for (int j = 0; j < 4; ++j)
            acc[i][j] = (i32x4){0, 0, 0, 0};

    const int rl   = lane & 15;
    const int slot = ((lane >> 4) ^ (rl & 3)) * 16;   // swizzled read slot
    const int wo   = (wv >> 1) * 64;
    const int wm   = (wv & 1) * 64;
    const int base_w = (wo + rl) * 64 + slot;
    const int base_a = 8192 + (wm + rl) * 64 + slot;

    auto STAGE = [&](int s, int kbuf) {
        int tap  = s >> 2;
        int kh   = (tap >= 6) ? 2 : ((tap >= 3) ? 1 : 0);
        int kw   = tap - kh * 3;
        int aoff = (kh * HPAD + kw) * CIN + (s & 3) * 64;
        int woff = s * 64;
        char* dst = lds_dst + kbuf * 16384;
        GLD16(w_g0 + woff, dst);
        GLD16(w_g1 + woff, dst + 4096);
        GLD16(a_g0 + aoff, dst + 8192);
        GLD16(a_g1 + aoff, dst + 12288);
    };

    // phase: stage s+3 into (K+3)&3, compute from buffer K, counted wait + raw barrier
    #define PHASE(S, K, WAITASM)                                               \
    {                                                                          \
        const int s_ = (S);                                                    \
        if (s_ + 3 < NSTEP) STAGE(s_ + 3, ((K) + 3) & 3);                      \
        const char* Wb = lds_flat + (K) * 16384;                               \
        i32x4 af[4], bf[4];                                                    \
        _Pragma("unroll") for (int i = 0; i < 4; ++i)                          \
            af[i] = *(const i32x4*)(Wb + base_w + i * 1024);                   \
        _Pragma("unroll") for (int j = 0; j < 4; ++j)                          \
            bf[j] = *(const i32x4*)(Wb + base_a + j * 1024);                   \
        _Pragma("unroll") for (int i = 0; i < 4; ++i)                          \
            _Pragma("unroll") for (int j = 0; j < 4; ++j)                      \
                acc[i][j] = __builtin_amdgcn_mfma_i32_16x16x64_i8(             \
                    af[i], bf[j], acc[i][j], 0, 0, 0);                         \
        asm volatile(WAITASM ::: "memory");                                    \
    }

    #define WAIT8 "s_waitcnt vmcnt(8) lgkmcnt(0)\n\ts_barrier"
    #define WAIT4 "s_waitcnt vmcnt(4) lgkmcnt(0)\n\ts_barrier"
    #define WAIT0 "s_waitcnt vmcnt(0) lgkmcnt(0)\n\ts_barrier"

    // prologue: stage 0,1,2; wait for 0; barrier
    STAGE(0, 0); STAGE(1, 1); STAGE(2, 2);
    asm volatile("s_waitcnt vmcnt(8)\n\ts_barrier" ::: "memory");

    for (int sb = 0; sb < 32; sb += 4) {
        PHASE(sb + 0, 0, WAIT8);
        PHASE(sb + 1, 1, WAIT8);
        PHASE(sb + 2, 2, WAIT8);
        PHASE(sb + 3, 3, WAIT8);
    }
    PHASE(32, 0, WAIT8);   // stages 35; waits stage 33
    PHASE(33, 1, WAIT4);   // waits stage 34
    PHASE(34, 2, WAIT0);   // waits stage 35
    PHASE(35, 3, "");      // last compute; no further staging

    // ---- epilogue: out[n][o][h][w] = acc * alpha[o] ----
    float al[4][4];
    #pragma unroll
    for (int i = 0; i < 4; ++i) {
        int ob = o0 + wo + i * 16 + (lane >> 4) * 4;
        #pragma unroll
        for (int r = 0; r < 4; ++r) al[i][r] = alpha[ob + r];
    }
    #pragma unroll
    for (int j = 0; j < 4; ++j) {
        int m  = m0 + wm + j * 16 + (lane & 15);
        int ni = m / SPATIAL;
        int sp = m - ni * SPATIAL;
        long base = (long)ni * (OCH * SPATIAL) + sp;
        #pragma unroll
        for (int i = 0; i < 4; ++i) {
            int ob = o0 + wo + i * 16 + (lane >> 4) * 4;
            #pragma unroll
            for (int r = 0; r < 4; ++r) {
                out[base + (long)(ob + r) * SPATIAL] = (float)acc[i][j][r] * al[i][r];
            }
        }
    }
    #undef PHASE
    #undef WAIT8
    #undef WAIT4
    #undef WAIT0
}

// =====================================================================
extern "C" void kernel_launch(void* const* d_in, const int* in_sizes, int n_in,
                              void* d_out, int out_size, void* d_ws, size_t ws_size,
                              hipStream_t stream) {
    const float* x  = (const float*)d_in[0];
    const float* w1 = (const float*)d_in[1];
    const float* w2 = (const float*)d_in[2];
    float* out = (float*)d_out;

    char* ws = (char*)d_ws;
    char*  xb    = ws;
    char*  WT    = ws + WT_OFF;
    float* alpha = (float*)(ws + ALPHA_OFF);

    hipLaunchKernelGGL(prep_weights, dim3(OCH), dim3(256), 0, stream, w1, w2, WT, alpha);
    hipLaunchKernelGGL(binarize_kernel, dim3(NIMG * HPAD), dim3(256), 0, stream, x, xb);
    hipLaunchKernelGGL(conv_kernel, dim3((M_TOT / 128) * 2), dim3(256), 0, stream,
                       xb, WT, alpha, out);
}

// Round 4
// 103.835 us; speedup vs baseline: 2.3515x; 1.0358x over previous
//
#include <hip/hip_runtime.h>
#include <hip/hip_bf16.h>
#include <stdint.h>

// ---- types ----
typedef __attribute__((ext_vector_type(4))) int i32x4;   // 16 i8 MFMA frag / i32x4 accum

typedef const void __attribute__((address_space(1)))* gas_ptr;
typedef void __attribute__((address_space(3)))* las_ptr;
#define GLD16(g, l) __builtin_amdgcn_global_load_lds((gas_ptr)(g), (las_ptr)(l), 16, 0, 0)

// ---- problem sizes ----
#define NIMG 32
#define CIN  256
#define HWDIM 56
#define HPAD 58
#define OCH  256
#define SPATIAL (HWDIM*HWDIM)        // 3136
#define M_TOT (NIMG*SPATIAL)         // 100352
#define KTOT  2304                    // 9*256
#define NSTEP 36                      // K-steps of 64 i8

// workspace layout (bytes)
#define WT_OFF     27557888ull        // after xb: 32*58*58*256 i8
#define ALPHA_OFF  28147712ull        // after WT: 256*2304 i8

#define LDSBUF 24576                  // W(8KB) + A(16KB)

// =====================================================================
// Kernel 1: per-o alpha + ternary i8 weights transposed to WT[o][k], k = tap*256 + c
// =====================================================================
__global__ __launch_bounds__(256)
void prep_weights(const float* __restrict__ w1, const float* __restrict__ w2,
                  char* __restrict__ WT, float* __restrict__ alpha) {
    const int o = blockIdx.x;
    const int t = threadIdx.x;
    const float* p1 = w1 + o * KTOT;
    const float* p2 = w2 + o * KTOT;
    char* wo = WT + o * KTOT;

    float s1 = 0.f, s2 = 0.f;
    for (int i = t; i < KTOT; i += 256) {
        float a = p1[i], b = p2[i];
        s1 += fabsf(a);
        s2 += fabsf(b);
        int sg = ((a > 0.f) ? 1 : ((a < 0.f) ? -1 : 0))
               + ((b > 0.f) ? 1 : ((b < 0.f) ? -1 : 0));
        int c = i / 9;
        int tap = i - c * 9;
        wo[tap * 256 + c] = (char)sg;
    }
    __shared__ float red[8];
    #pragma unroll
    for (int off = 32; off > 0; off >>= 1) {
        s1 += __shfl_down(s1, off, 64);
        s2 += __shfl_down(s2, off, 64);
    }
    const int lane = t & 63, wv = t >> 6;
    if (lane == 0) { red[wv] = s1; red[4 + wv] = s2; }
    __syncthreads();
    if (t == 0) {
        float t1 = red[0] + red[1] + red[2] + red[3];
        float t2 = red[4] + red[5] + red[6] + red[7];
        alpha[o] = (t1 * (1.f / 2304.f) + t2 * (1.f / 2304.f)) * 0.5f;
    }
}

// =====================================================================
// Kernel 2: binarize + NCHW -> padded NHWC i8, including border zeroing.
// Grid = 32 * 58 blocks: one per (n, hp).
// =====================================================================
__global__ __launch_bounds__(256)
void binarize_kernel(const float* __restrict__ x, char* __restrict__ xb) {
    const int b  = blockIdx.x;
    const int n  = b / HPAD;
    const int hp = b % HPAD;
    const int t  = threadIdx.x;
    char* rowp = xb + ((size_t)n * HPAD + hp) * (HPAD * CIN);

    if (hp == 0 || hp == HPAD - 1) {
        int* ip = (int*)rowp;                 // 58*256 B = 3712 ints
        for (int i = t; i < 3712; i += 256) ip[i] = 0;
        return;
    }
    const int h = hp - 1;
    __shared__ __align__(4) char tile[HWDIM * 260];
    if (t < 224) {
        const int w  = t % HWDIM;
        const int cl = t / HWDIM;
        const float* xp = x + (size_t)n * (CIN * SPATIAL) + (size_t)h * HWDIM + w;
        for (int c0 = 0; c0 < CIN; c0 += 4) {
            int c = c0 + cl;
            float v = xp[(size_t)c * SPATIAL];
            tile[w * 260 + c] = (v > 0.f) ? 1 : ((v < 0.f) ? -1 : 0);
        }
    }
    // zero left/right pad columns of this row
    int* ip = (int*)rowp;
    if (t < 64) ip[t] = 0;                    // w = 0
    else if (t < 128) ip[3648 + (t - 64)] = 0;// w = 57
    __syncthreads();
    const int wv = t >> 6, lane = t & 63;
    char* op = rowp + CIN;                    // w starts at 1
    for (int w0 = 0; w0 < HWDIM; w0 += 4) {
        int w = w0 + wv;
        int val = *(const int*)&tile[w * 260 + lane * 4];
        *(int*)(op + (size_t)w * CIN + lane * 4) = val;
    }
}

// =====================================================================
// Kernel 3: i8 implicit-GEMM. Block = 128(o) x 256(sp), 4 waves of 128x64.
// Ring-3 LDS (72KB -> 2 blocks/CU), counted vmcnt(6), 1 barrier/K-step.
// Bank swizzle f(r)=(r>>1)&3 applied both-sides (source-permute + read).
// =====================================================================
__global__ __launch_bounds__(256, 2)
void conv_kernel(const char* __restrict__ xb,
                 const char* __restrict__ WT,
                 const float* __restrict__ alpha,
                 float* __restrict__ out) {
    __shared__ __align__(16) char lds[3 * LDSBUF];

    const int t    = threadIdx.x;
    const int lane = t & 63;
    const int wv   = t >> 6;

    // XCD-aware bijective remap: 784 blocks = 8 XCDs * 98
    const int bid  = blockIdx.x;
    const int tid_ = (bid & 7) * 98 + (bid >> 3);
    const int nt   = tid_ & 1;        // o-tile (0/1)
    const int mt   = tid_ >> 1;       // sp-tile (0..391)
    const int o0   = nt * 128;
    const int m0   = mt * 256;

    // ---- staging sources ----
    // thread t: local row r = (t>>2) (+64q), phys slot p = t&3 holds k-slot p^f(r),
    // f(r) = (r>>1)&3 = (t>>3)&3 (invariant under r += 64).
    const int srow = t >> 2;
    const int scol = ((t & 3) ^ ((t >> 3) & 3)) * 16;
    const char* w_g0 = WT + (size_t)(o0 + srow) * KTOT + scol;
    const char* w_g1 = w_g0 + (size_t)64 * KTOT;
    const char* a_g[4];
    #pragma unroll
    for (int q = 0; q < 4; ++q) {
        int m  = m0 + srow + q * 64;
        int ni = m / SPATIAL;
        int sp = m - ni * SPATIAL;
        int h  = sp / HWDIM;
        int w  = sp - h * HWDIM;
        a_g[q] = xb + ((size_t)(ni * HPAD + h) * HPAD + w) * CIN + scol;
    }
    char* dstT = lds + t * 16;

    i32x4 acc[8][4];
    #pragma unroll
    for (int i = 0; i < 8; ++i)
        #pragma unroll
        for (int j = 0; j < 4; ++j)
            acc[i][j] = (i32x4){0, 0, 0, 0};

    // ---- read-side addressing ----
    const int rl    = lane & 15;
    const int slot  = ((lane >> 4) ^ ((rl >> 1) & 3)) * 16;  // swizzled 16B slot
    const int rdoff = rl * 64 + slot;
    const int aoffw = wv * 4096;       // wave's 64-sp slice in A part

    #define STAGE(S, B)                                                     \
    {                                                                       \
        const int s_ = (S);                                                 \
        const int tap = s_ >> 2;                                            \
        const int kh = tap / 3, kw = tap - kh * 3;                          \
        const int aoff = (kh * HPAD + kw) * CIN + (s_ & 3) * 64;            \
        const int woff = s_ * 64;                                           \
        char* d = dstT + (B) * LDSBUF;                                      \
        GLD16(w_g0 + woff, d);                                              \
        GLD16(w_g1 + woff, d + 4096);                                       \
        GLD16(a_g[0] + aoff, d + 8192);                                     \
        GLD16(a_g[1] + aoff, d + 12288);                                    \
        GLD16(a_g[2] + aoff, d + 16384);                                    \
        GLD16(a_g[3] + aoff, d + 20480);                                    \
    }

    #define COMPUTE(K)                                                      \
    {                                                                       \
        const char* Wb = lds + (K) * LDSBUF;                                \
        const char* Ab = Wb + 8192 + aoffw;                                 \
        i32x4 af[8], bf[4];                                                 \
        _Pragma("unroll") for (int i = 0; i < 8; ++i)                       \
            af[i] = *(const i32x4*)(Wb + i * 1024 + rdoff);                 \
        _Pragma("unroll") for (int j = 0; j < 4; ++j)                       \
            bf[j] = *(const i32x4*)(Ab + j * 1024 + rdoff);                 \
        __builtin_amdgcn_s_setprio(1);                                      \
        _Pragma("unroll") for (int i = 0; i < 8; ++i)                       \
            _Pragma("unroll") for (int j = 0; j < 4; ++j)                   \
                acc[i][j] = __builtin_amdgcn_mfma_i32_16x16x64_i8(          \
                    af[i], bf[j], acc[i][j], 0, 0, 0);                      \
        __builtin_amdgcn_s_setprio(0);                                      \
    }

    // prologue: stage 0,1 (12 loads); wait for stage 0 (vmcnt 6); barrier
    STAGE(0, 0);
    STAGE(1, 1);
    asm volatile("s_waitcnt vmcnt(6)\n\ts_barrier" ::: "memory");

    // steps 0..33: stage s+2, compute s, wait stage s+1 done (vmcnt 6), barrier
    #pragma unroll
    for (int s = 0; s < 34; ++s) {
        STAGE(s + 2, (s + 2) % 3);
        COMPUTE(s % 3);
        asm volatile("s_waitcnt vmcnt(6) lgkmcnt(0)\n\ts_barrier" ::: "memory");
    }
    // step 34: compute buf 1; wait stage 35 done; barrier
    COMPUTE(1);
    asm volatile("s_waitcnt vmcnt(0) lgkmcnt(0)\n\ts_barrier" ::: "memory");
    // step 35: compute buf 2
    COMPUTE(2);

    // ---- epilogue: out[n][o][h][w] = acc * alpha[o] ----
    // D frag: col(sp) = lane&15, row(o) = (lane>>4)*4 + reg
    #pragma unroll
    for (int i = 0; i < 8; ++i) {
        const int ob = o0 + i * 16 + (lane >> 4) * 4;
        float al[4];
        #pragma unroll
        for (int r = 0; r < 4; ++r) al[r] = alpha[ob + r];
        #pragma unroll
        for (int j = 0; j < 4; ++j) {
            int m  = m0 + wv * 64 + j * 16 + rl;
            int ni = m / SPATIAL;
            int sp = m - ni * SPATIAL;
            long base = (long)ni * (OCH * SPATIAL) + sp;
            #pragma unroll
            for (int r = 0; r < 4; ++r) {
                out[base + (long)(ob + r) * SPATIAL] = (float)acc[i][j][r] * al[r];
            }
        }
    }
    #undef STAGE
    #undef COMPUTE
}

// =====================================================================
extern "C" void kernel_launch(void* const* d_in, const int* in_sizes, int n_in,
                              void* d_out, int out_size, void* d_ws, size_t ws_size,
                              hipStream_t stream) {
    const float* x  = (const float*)d_in[0];
    const float* w1 = (const float*)d_in[1];
    const float* w2 = (const float*)d_in[2];
    float* out = (float*)d_out;

    char* ws = (char*)d_ws;
    char*  xb    = ws;
    char*  WT    = ws + WT_OFF;
    float* alpha = (float*)(ws + ALPHA_OFF);

    hipLaunchKernelGGL(prep_weights, dim3(OCH), dim3(256), 0, stream, w1, w2, WT, alpha);
    hipLaunchKernelGGL(binarize_kernel, dim3(NIMG * HPAD), dim3(256), 0, stream, x, xb);
    hipLaunchKernelGGL(conv_kernel, dim3(M_TOT / 128), dim3(256), 0, stream,
                       xb, WT, alpha, out);
}